// Round 19
// baseline (185.473 us; speedup 1.0000x reference)
//
#include <hip/hip_runtime.h>
#include <hip/hip_bf16.h>

typedef __hip_bfloat16 bf16;
typedef float f32x4 __attribute__((ext_vector_type(4)));
typedef float fvec4 __attribute__((ext_vector_type(4)));
typedef short s16x8 __attribute__((ext_vector_type(8)));

#define NB_B 2
#define NB_S 2048
#define NB_E 1024
#define NB_H 16
#define NB_D 64

typedef const __attribute__((address_space(1))) void* GPTR;
typedef __attribute__((address_space(3))) void* LPTR;

__device__ __forceinline__ void gld16(const void* g, void* l) {
  __builtin_amdgcn_global_load_lds((GPTR)g, (LPTR)l, 16, 0, 0);
}

__device__ __forceinline__ s16x8 ld8(const bf16* p) { return *(const s16x8*)p; }

__device__ __forceinline__ f32x4 MFMA(s16x8 a, s16x8 b, f32x4 c) {
  return __builtin_amdgcn_mfma_f32_16x16x32_bf16(a, b, c, 0, 0, 0);
}

struct __align__(8) bf16x4 { bf16 a, b, c, d; };

// ---------------- fused prep: converts + lambda + gnp-zero (+ combo if room) --
__global__ void prep_kernel(const float* __restrict__ inputs,
                            const float* __restrict__ wq, const float* __restrict__ wk,
                            const float* __restrict__ wv, const float* __restrict__ wo,
                            const float* __restrict__ lq1, const float* __restrict__ lq2,
                            const float* __restrict__ lk1, const float* __restrict__ lk2,
                            const int* __restrict__ tok, const float* __restrict__ amask,
                            bf16* __restrict__ xbf,
                            bf16* __restrict__ oq, bf16* __restrict__ ok,
                            bf16* __restrict__ ov, bf16* __restrict__ oo,
                            float* __restrict__ lamo, float* __restrict__ gnp,
                            float* __restrict__ comboOut) {
  const int blk = blockIdx.x;
  if (blk < 4096) {
    int i = blk * 256 + threadIdx.x;
    fvec4 v = ((const fvec4*)inputs)[i];
    bf16x4 o = { bf16(v.x), bf16(v.y), bf16(v.z), bf16(v.w) };
    ((bf16x4*)xbf)[i] = o;
  } else if (blk < 10240) {
    int i = (blk - 4096) * 256 + threadIdx.x;
    const float* src; bf16* dst; int off;
    if (i < 524288)       { src = wq; dst = oq; off = i; }
    else if (i < 1048576) { src = wk; dst = ok; off = i - 524288; }
    else if (i < 1310720) { src = wv; dst = ov; off = i - 1048576; }
    else                  { src = wo; dst = oo; off = i - 1310720; }
    fvec4 v = ((const fvec4*)src)[off];
    bf16x4 o = { bf16(v.x), bf16(v.y), bf16(v.z), bf16(v.w) };
    ((bf16x4*)dst)[off] = o;
  } else if (blk == 10240) {
    int l = threadIdx.x;
    if (l < 64) {
      float d1 = lq1[l] * lk1[l];
      float d2 = lq2[l] * lk2[l];
#pragma unroll
      for (int o = 32; o; o >>= 1) { d1 += __shfl_xor(d1, o); d2 += __shfl_xor(d2, o); }
      if (l == 0) lamo[0] = expf(d1) - expf(d2) + 0.8f;
    } else if (l < 192) {
      gnp[l - 64] = 0.f;  // zero 128 floats (GN atomic accumulators)
    }
  } else {
    int i = (blk - 10241) * 256 + threadIdx.x;  // combo: H*B*S = 65536
    int hh = i >> 12, bs = i & 4095;
    float slopeL = exp2f(-0.5f * (float)(hh + 1)) * 1.44269504088896340736f;
    comboOut[i] = slopeL * (float)tok[bs] + (amask[bs] - 1.f) * 1.44269504e9f;
  }
}

// ---------------- standalone combo (fallback when ws lacks fresh space) ------
__global__ void combo_kernel(const int* __restrict__ tok, const float* __restrict__ amask,
                             float* __restrict__ combo) {
  int i = blockIdx.x * 256 + threadIdx.x;
  int hh = i >> 12, bs = i & 4095;
  float slopeL = exp2f(-0.5f * (float)(hh + 1)) * 1.44269504088896340736f;
  combo[i] = slopeL * (float)tok[bs] + (amask[bs] - 1.f) * 1.44269504e9f;
}

// ---------------- GEMM: C = A @ B^T (2-phase double-buffered, 2-D grid) ------
// NOTE (R9): XCD-chunking re-fetched A 8x, cost ~19us. dim3(32,N) keeps locality.
// NOTE (R14/R15): GN fusion into GEMM regressed 11-35us; keep gld + gn_apply.
template <int EPI>
__global__ __launch_bounds__(256) void gemm_bt(const bf16* __restrict__ A,
                                               const bf16* __restrict__ Bw,
                                               bf16* __restrict__ Ob,
                                               bf16* __restrict__ Ob2,
                                               bf16* __restrict__ Ob3,
                                               float* __restrict__ Of,
                                               int Kd, float oscale) {
  __shared__ bf16 As[2][128 * 32];
  __shared__ bf16 Bs[2][128 * 32];
  const int tid = threadIdx.x;
  const int lane = tid & 63;
  const int fr = lane & 15, fq = lane >> 4;
  const int wave = tid >> 6;
  const int wr = (wave >> 1) * 64, wc = (wave & 1) * 64;
  const size_t m0 = (size_t)blockIdx.x * 128, n0 = (size_t)blockIdx.y * 128;

  f32x4 acc[4][4];
#pragma unroll
  for (int i = 0; i < 4; i++)
#pragma unroll
    for (int j = 0; j < 4; j++) acc[i][j] = f32x4{0.f, 0.f, 0.f, 0.f};

  const int ca = tid, cb = tid + 256;
  const bf16* ga0 = A + (m0 + (ca >> 2)) * Kd + (ca & 3) * 8;
  const bf16* ga1 = A + (m0 + (cb >> 2)) * Kd + (cb & 3) * 8;
  const bf16* gb0 = Bw + (n0 + (ca >> 2)) * Kd + (ca & 3) * 8;
  const bf16* gb1 = Bw + (n0 + (cb >> 2)) * Kd + (cb & 3) * 8;

  gld16(ga0, &As[0][ca * 8]);
  gld16(ga1, &As[0][cb * 8]);
  gld16(gb0, &Bs[0][ca * 8]);
  gld16(gb1, &Bs[0][cb * 8]);
  __syncthreads();

  const int NKT = Kd >> 5;
  for (int kti = 0; kti < NKT; ++kti) {
    const int cur = kti & 1;
    if (kti + 1 < NKT) {
      const int kt = (kti + 1) << 5;
      gld16(ga0 + kt, &As[cur ^ 1][ca * 8]);
      gld16(ga1 + kt, &As[cur ^ 1][cb * 8]);
      gld16(gb0 + kt, &Bs[cur ^ 1][ca * 8]);
      gld16(gb1 + kt, &Bs[cur ^ 1][cb * 8]);
    }
    s16x8 af[4], bfv[4];
#pragma unroll
    for (int mi = 0; mi < 4; mi++) af[mi] = ld8(&As[cur][(wr + mi * 16 + fr) * 32 + fq * 8]);
#pragma unroll
    for (int ni = 0; ni < 4; ni++) bfv[ni] = ld8(&Bs[cur][(wc + ni * 16 + fr) * 32 + fq * 8]);
#pragma unroll
    for (int mi = 0; mi < 4; mi++)
#pragma unroll
      for (int ni = 0; ni < 4; ni++)
        acc[mi][ni] = MFMA(af[mi], bfv[ni], acc[mi][ni]);
    __syncthreads();
  }

  bf16* dst = Ob;
  size_t nsub = 0;
  float osc = oscale;
  bool isV = false;
  if constexpr (EPI == 0) {
    if (n0 >= 4096)      { dst = Ob3; nsub = 4096; osc = 1.0f; isV = true; }
    else if (n0 >= 2048) { dst = Ob2; nsub = 2048; osc = 1.0f; }
  }

  if constexpr (EPI == 0) {
    if (isV) {
#pragma unroll
      for (int mi = 0; mi < 4; mi++)
#pragma unroll
        for (int ni = 0; ni < 4; ni++) {
          size_t m = m0 + wr + mi * 16 + fq * 4;
          size_t n = n0 + wc + ni * 16 + fr;
          size_t nn = n - 4096;
          size_t b = m >> 11, s = m & 2047, h = nn >> 6, d = nn & 63;
          bf16x4 o = { bf16(acc[mi][ni][0]), bf16(acc[mi][ni][1]),
                       bf16(acc[mi][ni][2]), bf16(acc[mi][ni][3]) };
          *(bf16x4*)&dst[((b * NB_H + h) * NB_D + d) * NB_S + s] = o;
        }
    } else {
#pragma unroll
      for (int mi = 0; mi < 4; mi++)
#pragma unroll
        for (int ni = 0; ni < 4; ni++)
#pragma unroll
          for (int i = 0; i < 4; i++) {
            size_t m = m0 + wr + mi * 16 + fq * 4 + i;
            size_t n = n0 + wc + ni * 16 + fr;
            float v = acc[mi][ni][i] * osc;
            size_t nn = n - nsub;
            size_t b = m >> 11, s = m & 2047, h = nn >> 7, dd = nn & 127;
            dst[((b * NB_H + h) * NB_S + s) * 128 + dd] = bf16(v);
          }
    }
  } else {
#pragma unroll
    for (int mi = 0; mi < 4; mi++)
#pragma unroll
      for (int ni = 0; ni < 4; ni++)
#pragma unroll
        for (int i = 0; i < 4; i++) {
          size_t m = m0 + wr + mi * 16 + fq * 4 + i;
          size_t n = n0 + wc + ni * 16 + fr;
          Of[m * 1024 + n] = acc[mi][ni][i] * oscale;
        }
  }
}

// ---------------- fused causal differential flash attention (swapped QK^T) ----
// R18 structure; R19: gs scratch ALIASED into Ps (dead after main loop) so LDS
// = Ks(32K)+Vs(16K)+Ps(32K) = exactly 80KB -> 2 blocks/CU (was 82.4KB -> 1).
__global__ __launch_bounds__(512, 2) void attn_kernel(
    const bf16* __restrict__ Q, const bf16* __restrict__ Kk, const bf16* __restrict__ Vt,
    const float* __restrict__ combo,
    const float* __restrict__ lamp, bf16* __restrict__ Xb, float* __restrict__ gnp) {
  __shared__ bf16 Ks[2][2][4096];  // [buf][set][64 k][64 d] swizzled  (32 KB)
  __shared__ bf16 Vs[2][4096];     // [buf][64 d][64 s] swizzled       (16 KB)
  __shared__ bf16 Ps[8][2048];     // per-wave P, set0 | set1 halves   (32 KB)

  const int tid = threadIdx.x, lane = tid & 63, wave = tid >> 6;
  const int fr = lane & 15, fq = lane >> 4;
  const int id = blockIdx.x;
  const int w = id >> 3;
  const int bh = (id & 7) * 4 + (w & 3);
  const int qj = 15 - (w >> 2);
  const int b = bh >> 4, h = bh & 15;

  const float lam = lamp[0];
  const float* comboH = combo + ((size_t)h * NB_B + b) * NB_S;

  const bf16* Kbase = Kk + (size_t)bh * NB_S * 128;
  const bf16* Vbase = Vt + (size_t)bh * NB_D * NB_S;

  const s16x8 onesv = { 0x3F80, 0x3F80, 0x3F80, 0x3F80, 0x3F80, 0x3F80, 0x3F80, 0x3F80 };

  // ---- tile-invariant LDS element offsets, pinned in registers ----
  int adr[4][2], pw[4], pr[2];
#pragma unroll
  for (int nt = 0; nt < 4; nt++) {
    const int r = nt * 16 + fr;
#pragma unroll
    for (int kk = 0; kk < 2; kk++) adr[nt][kk] = r * 64 + (((kk * 4 + fq) ^ (r & 7)) << 3);
    pw[nt] = fr * 64 + (((nt * 4 + fq) ^ ((fr & 7) << 1)) << 2);
  }
  pr[0] = fr * 64 + (((fq * 2) ^ ((fr & 7) << 1)) << 2);
  pr[1] = fr * 64 + (((8 + fq * 2) ^ ((fr & 7) << 1)) << 2);

  const bf16* gK[2]; int lK[2];
#pragma unroll
  for (int i = 0; i < 2; i++) {
    int c = tid + i * 512, set = c >> 9, cc = c & 511;
    int row = cc >> 3, col8 = cc & 7, sc = col8 ^ (row & 7);
    gK[i] = Kbase + (size_t)row * 128 + set * 64 + sc * 8;
    lK[i] = set * 4096 + cc * 8;
  }
  const bf16* gV; int lV;
  {
    int c = tid;
    int row = c >> 3, col8 = c & 7, sc = col8 ^ (row & 7);
    gV = Vbase + (size_t)row * NB_S + sc * 8;
    lV = c * 8;
  }

  const int q0 = qj * 128;
  const int qw = q0 + wave * 16;
  const int ntiles = 2 * qj + 2;

  const bf16* qrow = Q + ((size_t)bh * NB_S + qw + fr) * 128;
  s16x8 q1[2], q2[2];
  q1[0] = ld8(qrow + fq * 8);       q1[1] = ld8(qrow + 32 + fq * 8);
  q2[0] = ld8(qrow + 64 + fq * 8);  q2[1] = ld8(qrow + 96 + fq * 8);

  const int qg = qw + fr;

  float m = -1e30f;  // SHARED running max (valid: bias common, per-set denom)
  f32x4 acc1[4], acc2[4];
  f32x4 accL1 = f32x4{0.f,0.f,0.f,0.f}, accL2 = f32x4{0.f,0.f,0.f,0.f};
#pragma unroll
  for (int nt = 0; nt < 4; nt++) { acc1[nt] = f32x4{0.f,0.f,0.f,0.f}; acc2[nt] = f32x4{0.f,0.f,0.f,0.f}; }

  // prologue: stage K[0] + V[0] into buf 0; load combo tile 0
#pragma unroll
  for (int i = 0; i < 2; i++) gld16(gK[i], &Ks[0][0][0] + lK[i]);
  gld16(gV, &Vs[0][0] + lV);
  fvec4 cmb[4];
#pragma unroll
  for (int nt = 0; nt < 4; nt++) cmb[nt] = *(const fvec4*)(comboH + nt * 16 + fq * 4);
  __syncthreads();

  for (int t = 0; t < ntiles; ++t) {
    const int cur = t & 1;
    const int kv0 = t * 64;
    if (t + 1 < ntiles) {
#pragma unroll
      for (int i = 0; i < 2; i++)
        gld16(gK[i] + (size_t)(kv0 + 64) * 128, &Ks[cur ^ 1][0][0] + lK[i]);
      gld16(gV + (size_t)(kv0 + 64), &Vs[cur ^ 1][0] + lV);
    }

    const bool active = (kv0 <= qw + 15);  // wave-uniform causal skip
    if (active) {
      const bf16* kb0 = &Ks[cur][0][0];
      const bf16* kb1 = &Ks[cur][1][0];

      // ---- QK^T swapped: S[k][q]; bias enters as kk=0's C-operand ----
      f32x4 c1[4], c2[4];
      __builtin_amdgcn_s_setprio(1);
#pragma unroll
      for (int nt = 0; nt < 4; nt++) {
        c1[nt] = MFMA(ld8(kb0 + adr[nt][0]), q1[0], cmb[nt]);
        c2[nt] = MFMA(ld8(kb1 + adr[nt][0]), q2[0], cmb[nt]);
      }
      // cmb dead -> reload for t+1 (no copy; clamped at last tile)
      {
        const float* cp = comboH + (t + 1 < ntiles ? kv0 + 64 : kv0);
#pragma unroll
        for (int nt = 0; nt < 4; nt++) cmb[nt] = *(const fvec4*)(cp + nt * 16 + fq * 4);
      }
#pragma unroll
      for (int nt = 0; nt < 4; nt++) {
        c1[nt] = MFMA(ld8(kb0 + adr[nt][1]), q1[1], c1[nt]);
        c2[nt] = MFMA(ld8(kb1 + adr[nt][1]), q2[1], c2[nt]);
      }
      __builtin_amdgcn_s_setprio(0);

      if (kv0 + 63 > qw) {  // tile overlaps diagonal: causal mask
#pragma unroll
        for (int nt = 0; nt < 4; nt++)
#pragma unroll
          for (int i = 0; i < 4; i++)
            if (kv0 + nt * 16 + fq * 4 + i > qg) { c1[nt][i] = -1e30f; c2[nt][i] = -1e30f; }
      }

      s16x8 vf[4][2];
#pragma unroll
      for (int nt = 0; nt < 4; nt++)
#pragma unroll
        for (int kk = 0; kk < 2; kk++)
          vf[nt][kk] = ld8(&Vs[cur][adr[nt][kk]]);

      // ---- shared-max reduce over BOTH sets (interleaved trees) ----
      float av[4];
#pragma unroll
      for (int nt = 0; nt < 4; nt++) {
        const float x1 = fmaxf(fmaxf(c1[nt][0], c1[nt][1]), fmaxf(c1[nt][2], c1[nt][3]));
        const float x2 = fmaxf(fmaxf(c2[nt][0], c2[nt][1]), fmaxf(c2[nt][2], c2[nt][3]));
        av[nt] = fmaxf(x1, x2);
      }
      float pm = fmaxf(fmaxf(av[0], av[1]), fmaxf(av[2], av[3]));
      pm = fmaxf(pm, __shfl_xor(pm, 16));
      pm = fmaxf(pm, __shfl_xor(pm, 32));

      if (__any(pm > m + 8.f)) {  // defer-max (T13), one branch for both sets
        const float nm = fmaxf(m, pm);
        const float cor = exp2f(m - nm);
        m = nm;
#pragma unroll
        for (int i = 0; i < 4; i++) {
          const float ci = __shfl(cor, fq * 4 + i);
          accL1[i] *= ci; accL2[i] *= ci;
#pragma unroll
          for (int nt = 0; nt < 4; nt++) { acc1[nt][i] *= ci; acc2[nt][i] *= ci; }
        }
      }

      // ---- both P tiles -> LDS (set0 half | set1 half) before ANY PV ----
#pragma unroll
      for (int nt = 0; nt < 4; nt++) {
        bf16x4 pk1 = { bf16(exp2f(c1[nt][0] - m)), bf16(exp2f(c1[nt][1] - m)),
                       bf16(exp2f(c1[nt][2] - m)), bf16(exp2f(c1[nt][3] - m)) };
        bf16x4 pk2 = { bf16(exp2f(c2[nt][0] - m)), bf16(exp2f(c2[nt][1] - m)),
                       bf16(exp2f(c2[nt][2] - m)), bf16(exp2f(c2[nt][3] - m)) };
        *(bf16x4*)&Ps[wave][pw[nt]] = pk1;
        *(bf16x4*)&Ps[wave][1024 + pw[nt]] = pk2;
      }

      // ---- single 20-MFMA PV cluster (both sets; no mid-cluster lgkm) ----
      __builtin_amdgcn_s_setprio(1);
#pragma unroll
      for (int kk = 0; kk < 2; kk++) {
        const s16x8 pa1 = ld8(&Ps[wave][pr[kk]]);
        const s16x8 pa2 = ld8(&Ps[wave][1024 + pr[kk]]);
        accL1 = MFMA(pa1, onesv, accL1);
        accL2 = MFMA(pa2, onesv, accL2);
#pragma unroll
        for (int nt = 0; nt < 4; nt++) {
          acc1[nt] = MFMA(pa1, vf[nt][kk], acc1[nt]);
          acc2[nt] = MFMA(pa2, vf[nt][kk], acc2[nt]);
        }
      }
      __builtin_amdgcn_s_setprio(0);
    }  // active

    __syncthreads();  // drains staging; protects buf cur^1 WAR; orders last Ps reads
  }

  // ---- finalize: out = acc1/L1 - lam * acc2/L2 (all lane-local) ----
  float r1b[4], r2b[4];
#pragma unroll
  for (int i = 0; i < 4; i++) { r1b[i] = 1.f / accL1[i]; r2b[i] = lam / accL2[i]; }
  float s = 0.f, s2 = 0.f;
#pragma unroll
  for (int nt = 0; nt < 4; nt++)
#pragma unroll
    for (int i = 0; i < 4; i++) {
      const float v = acc1[nt][i] * r1b[i] - acc2[nt][i] * r2b[i];
      Xb[((size_t)bh * NB_S + qw + fq * 4 + i) * NB_D + nt * 16 + fr] = bf16(v);
      s += v; s2 += v * v;
    }
  // GN partial sums: wave reduce -> Ps-aliased scratch -> one atomic pair/block
  // (Ps dead after main loop; final loop __syncthreads ordered the last reads)
  float* gsp = (float*)&Ps[0][0];
#pragma unroll
  for (int o = 32; o; o >>= 1) { s += __shfl_xor(s, o); s2 += __shfl_xor(s2, o); }
  if (lane == 0) { gsp[wave * 2] = s; gsp[wave * 2 + 1] = s2; }
  __syncthreads();
  if (tid == 0) {
    float S = 0.f, S2 = 0.f;
#pragma unroll
    for (int i = 0; i < 8; i++) { S += gsp[i * 2]; S2 += gsp[i * 2 + 1]; }
    atomicAdd(&gnp[bh * 2], S);
    atomicAdd(&gnp[bh * 2 + 1], S2);
  }
}

// ---------------- GroupNorm apply (stats from attn atomics) ----------------
__global__ __launch_bounds__(256) void gn_apply(const bf16* __restrict__ Xb,
                                                const float* __restrict__ gnp,
                                                const float* __restrict__ gw,
                                                const float* __restrict__ gb,
                                                bf16* __restrict__ Xn) {
  const int blk = blockIdx.x, bh = blk >> 3, seg = blk & 7;
  const int b = bh >> 4, h = bh & 15;
  const float mean = gnp[bh * 2] * (1.f / 131072.f);
  const float var = gnp[bh * 2 + 1] * (1.f / 131072.f) - mean * mean;
  const float rstd = rsqrtf(var + 1e-5f) * 0.2f;  // fold (1-LAMBDA_INIT)
  const int tid = threadIdx.x;
  const int d0 = (tid * 8) & 63;
  const int c = h * 64 + d0;
  fvec4 w0 = *(const fvec4*)(gw + c), w1 = *(const fvec4*)(gw + c + 4);
  fvec4 b0 = *(const fvec4*)(gb + c), b1 = *(const fvec4*)(gb + c + 4);
  float wv[8] = { w0.x, w0.y, w0.z, w0.w, w1.x, w1.y, w1.z, w1.w };
  float bv[8] = { b0.x, b0.y, b0.z, b0.w, b1.x, b1.y, b1.z, b1.w };
  const bf16* xp = Xb + (size_t)bh * 131072;
#pragma unroll
  for (int jj = 0; jj < 8; jj++) {
    const int e = seg * 16384 + (tid + jj * 256) * 8;
    const int srow = e >> 6;
    s16x8 xv = *(const s16x8*)(xp + e);
    bf16 o8[8];
#pragma unroll
    for (int k = 0; k < 8; k++) {
      const float xf = __uint_as_float(((unsigned)(unsigned short)xv[k]) << 16);
      o8[k] = bf16((xf - mean) * rstd * wv[k] + 0.2f * bv[k]);
    }
    *(s16x8*)(Xn + ((size_t)b * NB_S + srow) * 1024 + c) = *(const s16x8*)o8;
  }
}

// ---------------- launch ----------------
extern "C" void kernel_launch(void* const* d_in, const int* in_sizes, int n_in,
                              void* d_out, int out_size, void* d_ws, size_t ws_size,
                              hipStream_t stream) {
  const float* inputs = (const float*)d_in[0];
  const float* amask  = (const float*)d_in[1];
  const int*   tok    = (const int*)d_in[2];
  const float* Wq = (const float*)d_in[3];
  const float* Wk = (const float*)d_in[4];
  const float* Wv = (const float*)d_in[5];
  const float* Wo = (const float*)d_in[6];
  const float* lq1 = (const float*)d_in[7];
  const float* lq2 = (const float*)d_in[8];
  const float* lk1 = (const float*)d_in[9];
  const float* lk2 = (const float*)d_in[10];
  const float* gw = (const float*)d_in[11];
  const float* gb = (const float*)d_in[12];
  float* out = (float*)d_out;
  char* ws = (char*)d_ws;

  bf16* Xbf = (bf16*)(ws + 0);
  bf16* Wqb = (bf16*)(ws + 8388608);       // Wqb||Wkb||Wvb contiguous -> fused QKV
  bf16* Wkb = (bf16*)(ws + 12582912);
  bf16* Wvb = (bf16*)(ws + 16777216);      // dead after QKV gemm
  bf16* Xb  = (bf16*)(ws + 0);             // attn out bf16; aliases Xbf (dead by attn)
  float* comboAlias = (float*)(ws + 16777216);  // aliases Wvb (fallback path)
  bf16* Qb  = (bf16*)(ws + 18874368);
  bf16* Xn  = (bf16*)(ws + 18874368);      // aliases Qb (dead after attn)
  bf16* Kb  = (bf16*)(ws + 35651584);
  bf16* Vtb = (bf16*)(ws + 52428800);
  bf16* Wob = (bf16*)(ws + 60817408);
  float* lam = (float*)(ws + 62914560);
  float* gnp = (float*)(ws + 62914816);    // 128 floats (zeroed in prep)
  float* comboFresh = (float*)(ws + 62915584);  // 256KB fresh space (if ws allows)

  const bool foldCombo = (ws_size >= (size_t)62915584 + 262144);
  float* combo = foldCombo ? comboFresh : comboAlias;

  const float QSCALE = 0.125f * 1.44269504088896340736f;  // 1/sqrt(D) * log2(e)

  prep_kernel<<<foldCombo ? 10497 : 10241, 256, 0, stream>>>(
      inputs, Wq, Wk, Wv, Wo, lq1, lq2, lk1, lk2, tok, amask,
      Xbf, Wqb, Wkb, Wvb, Wob, lam, gnp, combo);

  // fused Q+K+V projection: B = Wqb||Wkb||Wvb (N=5120)
  gemm_bt<0><<<dim3(32, 40), 256, 0, stream>>>(Xbf, Wqb, Qb, Kb, Vtb, nullptr, 1024, QSCALE);

  if (!foldCombo)
    combo_kernel<<<256, 256, 0, stream>>>(tok, amask, combo);

  attn_kernel<<<512, 512, 0, stream>>>(Qb, Kb, Vtb, combo, lam, Xb, gnp);

  gn_apply<<<256, 256, 0, stream>>>(Xb, gnp, gw, gb, Xn);

  gemm_bt<2><<<dim3(32, 8), 256, 0, stream>>>(Xn, Wob, nullptr, nullptr, nullptr, out, 1024, 1.0f);
}

// Round 20
// 183.842 us; speedup vs baseline: 1.0089x; 1.0089x over previous
//
#include <hip/hip_runtime.h>
#include <hip/hip_bf16.h>

typedef __hip_bfloat16 bf16;
typedef float f32x4 __attribute__((ext_vector_type(4)));
typedef float fvec4 __attribute__((ext_vector_type(4)));
typedef short s16x8 __attribute__((ext_vector_type(8)));

#define NB_B 2
#define NB_S 2048
#define NB_E 1024
#define NB_H 16
#define NB_D 64

typedef const __attribute__((address_space(1))) void* GPTR;
typedef __attribute__((address_space(3))) void* LPTR;

__device__ __forceinline__ void gld16(const void* g, void* l) {
  __builtin_amdgcn_global_load_lds((GPTR)g, (LPTR)l, 16, 0, 0);
}

__device__ __forceinline__ s16x8 ld8(const bf16* p) { return *(const s16x8*)p; }

__device__ __forceinline__ f32x4 MFMA(s16x8 a, s16x8 b, f32x4 c) {
  return __builtin_amdgcn_mfma_f32_16x16x32_bf16(a, b, c, 0, 0, 0);
}

struct __align__(8) bf16x4 { bf16 a, b, c, d; };

// ---------------- fused prep: converts + lambda + gnp-zero (+ combo if room) --
__global__ void prep_kernel(const float* __restrict__ inputs,
                            const float* __restrict__ wq, const float* __restrict__ wk,
                            const float* __restrict__ wv, const float* __restrict__ wo,
                            const float* __restrict__ lq1, const float* __restrict__ lq2,
                            const float* __restrict__ lk1, const float* __restrict__ lk2,
                            const int* __restrict__ tok, const float* __restrict__ amask,
                            bf16* __restrict__ xbf,
                            bf16* __restrict__ oq, bf16* __restrict__ ok,
                            bf16* __restrict__ ov, bf16* __restrict__ oo,
                            float* __restrict__ lamo, float* __restrict__ gnp,
                            float* __restrict__ comboOut) {
  const int blk = blockIdx.x;
  if (blk < 4096) {
    int i = blk * 256 + threadIdx.x;
    fvec4 v = ((const fvec4*)inputs)[i];
    bf16x4 o = { bf16(v.x), bf16(v.y), bf16(v.z), bf16(v.w) };
    ((bf16x4*)xbf)[i] = o;
  } else if (blk < 10240) {
    int i = (blk - 4096) * 256 + threadIdx.x;
    const float* src; bf16* dst; int off;
    if (i < 524288)       { src = wq; dst = oq; off = i; }
    else if (i < 1048576) { src = wk; dst = ok; off = i - 524288; }
    else if (i < 1310720) { src = wv; dst = ov; off = i - 1048576; }
    else                  { src = wo; dst = oo; off = i - 1310720; }
    fvec4 v = ((const fvec4*)src)[off];
    bf16x4 o = { bf16(v.x), bf16(v.y), bf16(v.z), bf16(v.w) };
    ((bf16x4*)dst)[off] = o;
  } else if (blk == 10240) {
    int l = threadIdx.x;
    if (l < 64) {
      float d1 = lq1[l] * lk1[l];
      float d2 = lq2[l] * lk2[l];
#pragma unroll
      for (int o = 32; o; o >>= 1) { d1 += __shfl_xor(d1, o); d2 += __shfl_xor(d2, o); }
      if (l == 0) lamo[0] = expf(d1) - expf(d2) + 0.8f;
    } else if (l < 192) {
      gnp[l - 64] = 0.f;  // zero 128 floats (GN atomic accumulators)
    }
  } else {
    int i = (blk - 10241) * 256 + threadIdx.x;  // combo: H*B*S = 65536
    int hh = i >> 12, bs = i & 4095;
    float slopeL = exp2f(-0.5f * (float)(hh + 1)) * 1.44269504088896340736f;
    comboOut[i] = slopeL * (float)tok[bs] + (amask[bs] - 1.f) * 1.44269504e9f;
  }
}

// ---------------- standalone combo (fallback when ws lacks fresh space) ------
__global__ void combo_kernel(const int* __restrict__ tok, const float* __restrict__ amask,
                             float* __restrict__ combo) {
  int i = blockIdx.x * 256 + threadIdx.x;
  int hh = i >> 12, bs = i & 4095;
  float slopeL = exp2f(-0.5f * (float)(hh + 1)) * 1.44269504088896340736f;
  combo[i] = slopeL * (float)tok[bs] + (amask[bs] - 1.f) * 1.44269504e9f;
}

// ---------------- GEMM: C = A @ B^T (2-phase double-buffered, 2-D grid) ------
// NOTE (R9): XCD-chunking re-fetched A 8x, cost ~19us. dim3(32,N) keeps locality.
// NOTE (R14/R15): GN fusion into GEMM regressed 11-35us; keep gld + gn_apply.
// EPI 0 (fused QKV, N=5120): n<2048 -> Ob=Q (scaled); n<4096 -> Ob2=K;
//                            else   -> Ob3=V transposed [b][h][d][s]
template <int EPI>
__global__ __launch_bounds__(256) void gemm_bt(const bf16* __restrict__ A,
                                               const bf16* __restrict__ Bw,
                                               bf16* __restrict__ Ob,
                                               bf16* __restrict__ Ob2,
                                               bf16* __restrict__ Ob3,
                                               float* __restrict__ Of,
                                               int Kd, float oscale) {
  __shared__ bf16 As[2][128 * 32];
  __shared__ bf16 Bs[2][128 * 32];
  const int tid = threadIdx.x;
  const int lane = tid & 63;
  const int fr = lane & 15, fq = lane >> 4;
  const int wave = tid >> 6;
  const int wr = (wave >> 1) * 64, wc = (wave & 1) * 64;
  const size_t m0 = (size_t)blockIdx.x * 128, n0 = (size_t)blockIdx.y * 128;

  f32x4 acc[4][4];
#pragma unroll
  for (int i = 0; i < 4; i++)
#pragma unroll
    for (int j = 0; j < 4; j++) acc[i][j] = f32x4{0.f, 0.f, 0.f, 0.f};

  const int ca = tid, cb = tid + 256;
  const bf16* ga0 = A + (m0 + (ca >> 2)) * Kd + (ca & 3) * 8;
  const bf16* ga1 = A + (m0 + (cb >> 2)) * Kd + (cb & 3) * 8;
  const bf16* gb0 = Bw + (n0 + (ca >> 2)) * Kd + (ca & 3) * 8;
  const bf16* gb1 = Bw + (n0 + (cb >> 2)) * Kd + (cb & 3) * 8;

  gld16(ga0, &As[0][ca * 8]);
  gld16(ga1, &As[0][cb * 8]);
  gld16(gb0, &Bs[0][ca * 8]);
  gld16(gb1, &Bs[0][cb * 8]);
  __syncthreads();

  const int NKT = Kd >> 5;
  for (int kti = 0; kti < NKT; ++kti) {
    const int cur = kti & 1;
    if (kti + 1 < NKT) {
      const int kt = (kti + 1) << 5;
      gld16(ga0 + kt, &As[cur ^ 1][ca * 8]);
      gld16(ga1 + kt, &As[cur ^ 1][cb * 8]);
      gld16(gb0 + kt, &Bs[cur ^ 1][ca * 8]);
      gld16(gb1 + kt, &Bs[cur ^ 1][cb * 8]);
    }
    s16x8 af[4], bfv[4];
#pragma unroll
    for (int mi = 0; mi < 4; mi++) af[mi] = ld8(&As[cur][(wr + mi * 16 + fr) * 32 + fq * 8]);
#pragma unroll
    for (int ni = 0; ni < 4; ni++) bfv[ni] = ld8(&Bs[cur][(wc + ni * 16 + fr) * 32 + fq * 8]);
#pragma unroll
    for (int mi = 0; mi < 4; mi++)
#pragma unroll
      for (int ni = 0; ni < 4; ni++)
        acc[mi][ni] = MFMA(af[mi], bfv[ni], acc[mi][ni]);
    __syncthreads();
  }

  bf16* dst = Ob;
  size_t nsub = 0;
  float osc = oscale;
  bool isV = false;
  if constexpr (EPI == 0) {
    if (n0 >= 4096)      { dst = Ob3; nsub = 4096; osc = 1.0f; isV = true; }
    else if (n0 >= 2048) { dst = Ob2; nsub = 2048; osc = 1.0f; }
  }

  if constexpr (EPI == 0) {
    if (isV) {
#pragma unroll
      for (int mi = 0; mi < 4; mi++)
#pragma unroll
        for (int ni = 0; ni < 4; ni++) {
          size_t m = m0 + wr + mi * 16 + fq * 4;
          size_t n = n0 + wc + ni * 16 + fr;
          size_t nn = n - 4096;
          size_t b = m >> 11, s = m & 2047, h = nn >> 6, d = nn & 63;
          bf16x4 o = { bf16(acc[mi][ni][0]), bf16(acc[mi][ni][1]),
                       bf16(acc[mi][ni][2]), bf16(acc[mi][ni][3]) };
          *(bf16x4*)&dst[((b * NB_H + h) * NB_D + d) * NB_S + s] = o;
        }
    } else {
#pragma unroll
      for (int mi = 0; mi < 4; mi++)
#pragma unroll
        for (int ni = 0; ni < 4; ni++)
#pragma unroll
          for (int i = 0; i < 4; i++) {
            size_t m = m0 + wr + mi * 16 + fq * 4 + i;
            size_t n = n0 + wc + ni * 16 + fr;
            float v = acc[mi][ni][i] * osc;
            size_t nn = n - nsub;
            size_t b = m >> 11, s = m & 2047, h = nn >> 7, dd = nn & 127;
            dst[((b * NB_H + h) * NB_S + s) * 128 + dd] = bf16(v);
          }
    }
  } else {
#pragma unroll
    for (int mi = 0; mi < 4; mi++)
#pragma unroll
      for (int ni = 0; ni < 4; ni++)
#pragma unroll
        for (int i = 0; i < 4; i++) {
          size_t m = m0 + wr + mi * 16 + fq * 4 + i;
          size_t n = n0 + wc + ni * 16 + fr;
          Of[m * 1024 + n] = acc[mi][ni][i] * oscale;
        }
  }
}

// ---------------- out-proj GEMM, BM=64 for occupancy (R20) -------------------
// Grid dim3(64,8) = 512 blocks (2/CU; old 128-tile was 256 = 1/CU, 1 wave/SIMD,
// pure latency-bound). 4 waves each own 64x32 (4x2 frags). LDS 24KB.
__global__ __launch_bounds__(256) void gemm_out64(const bf16* __restrict__ A,
                                                  const bf16* __restrict__ Bw,
                                                  float* __restrict__ Of) {
  __shared__ bf16 As[2][64 * 32];
  __shared__ bf16 Bs[2][128 * 32];
  const int tid = threadIdx.x;
  const int lane = tid & 63;
  const int fr = lane & 15, fq = lane >> 4;
  const int wave = tid >> 6;
  const int wc = wave * 32;
  const size_t m0 = (size_t)blockIdx.x * 64, n0 = (size_t)blockIdx.y * 128;

  f32x4 acc[4][2];
#pragma unroll
  for (int i = 0; i < 4; i++)
#pragma unroll
    for (int j = 0; j < 2; j++) acc[i][j] = f32x4{0.f, 0.f, 0.f, 0.f};

  const int ca = tid, cb = tid + 256;
  const bf16* ga0 = A + (m0 + (ca >> 2)) * 1024 + (ca & 3) * 8;      // 256 A-chunks
  const bf16* gb0 = Bw + (n0 + (ca >> 2)) * 1024 + (ca & 3) * 8;     // 512 B-chunks
  const bf16* gb1 = Bw + (n0 + (cb >> 2)) * 1024 + (cb & 3) * 8;

  gld16(ga0, &As[0][ca * 8]);
  gld16(gb0, &Bs[0][ca * 8]);
  gld16(gb1, &Bs[0][cb * 8]);
  __syncthreads();

  for (int kti = 0; kti < 32; ++kti) {
    const int cur = kti & 1;
    if (kti + 1 < 32) {
      const int kt = (kti + 1) << 5;
      gld16(ga0 + kt, &As[cur ^ 1][ca * 8]);
      gld16(gb0 + kt, &Bs[cur ^ 1][ca * 8]);
      gld16(gb1 + kt, &Bs[cur ^ 1][cb * 8]);
    }
    s16x8 af[4], bfv[2];
#pragma unroll
    for (int mi = 0; mi < 4; mi++) af[mi] = ld8(&As[cur][(mi * 16 + fr) * 32 + fq * 8]);
#pragma unroll
    for (int ni = 0; ni < 2; ni++) bfv[ni] = ld8(&Bs[cur][(wc + ni * 16 + fr) * 32 + fq * 8]);
#pragma unroll
    for (int mi = 0; mi < 4; mi++)
#pragma unroll
      for (int ni = 0; ni < 2; ni++)
        acc[mi][ni] = MFMA(af[mi], bfv[ni], acc[mi][ni]);
    __syncthreads();
  }

#pragma unroll
  for (int mi = 0; mi < 4; mi++)
#pragma unroll
    for (int ni = 0; ni < 2; ni++)
#pragma unroll
      for (int i = 0; i < 4; i++) {
        size_t m = m0 + mi * 16 + fq * 4 + i;
        size_t n = n0 + wc + ni * 16 + fr;
        Of[m * 1024 + n] = acc[mi][ni][i];
      }
}

// ---------------- fused causal differential flash attention (swapped QK^T) ----
// R18 structure (shared max + single 20-MFMA PV cluster); gs aliased into Ps.
__global__ __launch_bounds__(512, 2) void attn_kernel(
    const bf16* __restrict__ Q, const bf16* __restrict__ Kk, const bf16* __restrict__ Vt,
    const float* __restrict__ combo,
    const float* __restrict__ lamp, bf16* __restrict__ Xb, float* __restrict__ gnp) {
  __shared__ bf16 Ks[2][2][4096];  // [buf][set][64 k][64 d] swizzled  (32 KB)
  __shared__ bf16 Vs[2][4096];     // [buf][64 d][64 s] swizzled       (16 KB)
  __shared__ bf16 Ps[8][2048];     // per-wave P, set0 | set1 halves   (32 KB)

  const int tid = threadIdx.x, lane = tid & 63, wave = tid >> 6;
  const int fr = lane & 15, fq = lane >> 4;
  const int id = blockIdx.x;
  const int w = id >> 3;
  const int bh = (id & 7) * 4 + (w & 3);
  const int qj = 15 - (w >> 2);
  const int b = bh >> 4, h = bh & 15;

  const float lam = lamp[0];
  const float* comboH = combo + ((size_t)h * NB_B + b) * NB_S;

  const bf16* Kbase = Kk + (size_t)bh * NB_S * 128;
  const bf16* Vbase = Vt + (size_t)bh * NB_D * NB_S;

  const s16x8 onesv = { 0x3F80, 0x3F80, 0x3F80, 0x3F80, 0x3F80, 0x3F80, 0x3F80, 0x3F80 };

  int adr[4][2], pw[4], pr[2];
#pragma unroll
  for (int nt = 0; nt < 4; nt++) {
    const int r = nt * 16 + fr;
#pragma unroll
    for (int kk = 0; kk < 2; kk++) adr[nt][kk] = r * 64 + (((kk * 4 + fq) ^ (r & 7)) << 3);
    pw[nt] = fr * 64 + (((nt * 4 + fq) ^ ((fr & 7) << 1)) << 2);
  }
  pr[0] = fr * 64 + (((fq * 2) ^ ((fr & 7) << 1)) << 2);
  pr[1] = fr * 64 + (((8 + fq * 2) ^ ((fr & 7) << 1)) << 2);

  const bf16* gK[2]; int lK[2];
#pragma unroll
  for (int i = 0; i < 2; i++) {
    int c = tid + i * 512, set = c >> 9, cc = c & 511;
    int row = cc >> 3, col8 = cc & 7, sc = col8 ^ (row & 7);
    gK[i] = Kbase + (size_t)row * 128 + set * 64 + sc * 8;
    lK[i] = set * 4096 + cc * 8;
  }
  const bf16* gV; int lV;
  {
    int c = tid;
    int row = c >> 3, col8 = c & 7, sc = col8 ^ (row & 7);
    gV = Vbase + (size_t)row * NB_S + sc * 8;
    lV = c * 8;
  }

  const int q0 = qj * 128;
  const int qw = q0 + wave * 16;
  const int ntiles = 2 * qj + 2;

  const bf16* qrow = Q + ((size_t)bh * NB_S + qw + fr) * 128;
  s16x8 q1[2], q2[2];
  q1[0] = ld8(qrow + fq * 8);       q1[1] = ld8(qrow + 32 + fq * 8);
  q2[0] = ld8(qrow + 64 + fq * 8);  q2[1] = ld8(qrow + 96 + fq * 8);

  const int qg = qw + fr;

  float m = -1e30f;  // SHARED running max (valid: bias common, per-set denom)
  f32x4 acc1[4], acc2[4];
  f32x4 accL1 = f32x4{0.f,0.f,0.f,0.f}, accL2 = f32x4{0.f,0.f,0.f,0.f};
#pragma unroll
  for (int nt = 0; nt < 4; nt++) { acc1[nt] = f32x4{0.f,0.f,0.f,0.f}; acc2[nt] = f32x4{0.f,0.f,0.f,0.f}; }

  // prologue: stage K[0] + V[0] into buf 0; load combo tile 0
#pragma unroll
  for (int i = 0; i < 2; i++) gld16(gK[i], &Ks[0][0][0] + lK[i]);
  gld16(gV, &Vs[0][0] + lV);
  fvec4 cmb[4];
#pragma unroll
  for (int nt = 0; nt < 4; nt++) cmb[nt] = *(const fvec4*)(comboH + nt * 16 + fq * 4);
  __syncthreads();

  for (int t = 0; t < ntiles; ++t) {
    const int cur = t & 1;
    const int kv0 = t * 64;
    if (t + 1 < ntiles) {
#pragma unroll
      for (int i = 0; i < 2; i++)
        gld16(gK[i] + (size_t)(kv0 + 64) * 128, &Ks[cur ^ 1][0][0] + lK[i]);
      gld16(gV + (size_t)(kv0 + 64), &Vs[cur ^ 1][0] + lV);
    }

    const bool active = (kv0 <= qw + 15);  // wave-uniform causal skip
    if (active) {
      const bf16* kb0 = &Ks[cur][0][0];
      const bf16* kb1 = &Ks[cur][1][0];

      // ---- QK^T swapped: S[k][q]; bias enters as kk=0's C-operand ----
      f32x4 c1[4], c2[4];
      __builtin_amdgcn_s_setprio(1);
#pragma unroll
      for (int nt = 0; nt < 4; nt++) {
        c1[nt] = MFMA(ld8(kb0 + adr[nt][0]), q1[0], cmb[nt]);
        c2[nt] = MFMA(ld8(kb1 + adr[nt][0]), q2[0], cmb[nt]);
      }
      // cmb dead -> reload for t+1 (no copy; clamped at last tile)
      {
        const float* cp = comboH + (t + 1 < ntiles ? kv0 + 64 : kv0);
#pragma unroll
        for (int nt = 0; nt < 4; nt++) cmb[nt] = *(const fvec4*)(cp + nt * 16 + fq * 4);
      }
#pragma unroll
      for (int nt = 0; nt < 4; nt++) {
        c1[nt] = MFMA(ld8(kb0 + adr[nt][1]), q1[1], c1[nt]);
        c2[nt] = MFMA(ld8(kb1 + adr[nt][1]), q2[1], c2[nt]);
      }
      __builtin_amdgcn_s_setprio(0);

      if (kv0 + 63 > qw) {  // tile overlaps diagonal: causal mask
#pragma unroll
        for (int nt = 0; nt < 4; nt++)
#pragma unroll
          for (int i = 0; i < 4; i++)
            if (kv0 + nt * 16 + fq * 4 + i > qg) { c1[nt][i] = -1e30f; c2[nt][i] = -1e30f; }
      }

      s16x8 vf[4][2];
#pragma unroll
      for (int nt = 0; nt < 4; nt++)
#pragma unroll
        for (int kk = 0; kk < 2; kk++)
          vf[nt][kk] = ld8(&Vs[cur][adr[nt][kk]]);

      // ---- shared-max reduce over BOTH sets (interleaved trees) ----
      float av[4];
#pragma unroll
      for (int nt = 0; nt < 4; nt++) {
        const float x1 = fmaxf(fmaxf(c1[nt][0], c1[nt][1]), fmaxf(c1[nt][2], c1[nt][3]));
        const float x2 = fmaxf(fmaxf(c2[nt][0], c2[nt][1]), fmaxf(c2[nt][2], c2[nt][3]));
        av[nt] = fmaxf(x1, x2);
      }
      float pm = fmaxf(fmaxf(av[0], av[1]), fmaxf(av[2], av[3]));
      pm = fmaxf(pm, __shfl_xor(pm, 16));
      pm = fmaxf(pm, __shfl_xor(pm, 32));

      if (__any(pm > m + 8.f)) {  // defer-max (T13), one branch for both sets
        const float nm = fmaxf(m, pm);
        const float cor = exp2f(m - nm);
        m = nm;
#pragma unroll
        for (int i = 0; i < 4; i++) {
          const float ci = __shfl(cor, fq * 4 + i);
          accL1[i] *= ci; accL2[i] *= ci;
#pragma unroll
          for (int nt = 0; nt < 4; nt++) { acc1[nt][i] *= ci; acc2[nt][i] *= ci; }
        }
      }

      // ---- both P tiles -> LDS (set0 half | set1 half) before ANY PV ----
#pragma unroll
      for (int nt = 0; nt < 4; nt++) {
        bf16x4 pk1 = { bf16(exp2f(c1[nt][0] - m)), bf16(exp2f(c1[nt][1] - m)),
                       bf16(exp2f(c1[nt][2] - m)), bf16(exp2f(c1[nt][3] - m)) };
        bf16x4 pk2 = { bf16(exp2f(c2[nt][0] - m)), bf16(exp2f(c2[nt][1] - m)),
                       bf16(exp2f(c2[nt][2] - m)), bf16(exp2f(c2[nt][3] - m)) };
        *(bf16x4*)&Ps[wave][pw[nt]] = pk1;
        *(bf16x4*)&Ps[wave][1024 + pw[nt]] = pk2;
      }

      // ---- single 20-MFMA PV cluster (both sets; no mid-cluster lgkm) ----
      __builtin_amdgcn_s_setprio(1);
#pragma unroll
      for (int kk = 0; kk < 2; kk++) {
        const s16x8 pa1 = ld8(&Ps[wave][pr[kk]]);
        const s16x8 pa2 = ld8(&Ps[wave][1024 + pr[kk]]);
        accL1 = MFMA(pa1, onesv, accL1);
        accL2 = MFMA(pa2, onesv, accL2);
#pragma unroll
        for (int nt = 0; nt < 4; nt++) {
          acc1[nt] = MFMA(pa1, vf[nt][kk], acc1[nt]);
          acc2[nt] = MFMA(pa2, vf[nt][kk], acc2[nt]);
        }
      }
      __builtin_amdgcn_s_setprio(0);
    }  // active

    __syncthreads();  // drains staging; protects buf cur^1 WAR; orders last Ps reads
  }

  // ---- finalize: out = acc1/L1 - lam * acc2/L2 (all lane-local) ----
  float r1b[4], r2b[4];
#pragma unroll
  for (int i = 0; i < 4; i++) { r1b[i] = 1.f / accL1[i]; r2b[i] = lam / accL2[i]; }
  float s = 0.f, s2 = 0.f;
#pragma unroll
  for (int nt = 0; nt < 4; nt++)
#pragma unroll
    for (int i = 0; i < 4; i++) {
      const float v = acc1[nt][i] * r1b[i] - acc2[nt][i] * r2b[i];
      Xb[((size_t)bh * NB_S + qw + fq * 4 + i) * NB_D + nt * 16 + fr] = bf16(v);
      s += v; s2 += v * v;
    }
  // GN partial sums: wave reduce -> Ps-aliased scratch -> one atomic pair/block
  float* gsp = (float*)&Ps[0][0];
#pragma unroll
  for (int o = 32; o; o >>= 1) { s += __shfl_xor(s, o); s2 += __shfl_xor(s2, o); }
  if (lane == 0) { gsp[wave * 2] = s; gsp[wave * 2 + 1] = s2; }
  __syncthreads();
  if (tid == 0) {
    float S = 0.f, S2 = 0.f;
#pragma unroll
    for (int i = 0; i < 8; i++) { S += gsp[i * 2]; S2 += gsp[i * 2 + 1]; }
    atomicAdd(&gnp[bh * 2], S);
    atomicAdd(&gnp[bh * 2 + 1], S2);
  }
}

// ---------------- GroupNorm apply (R20: 512 blocks for 2x occupancy) ---------
__global__ __launch_bounds__(256) void gn_apply(const bf16* __restrict__ Xb,
                                                const float* __restrict__ gnp,
                                                const float* __restrict__ gw,
                                                const float* __restrict__ gb,
                                                bf16* __restrict__ Xn) {
  const int blk = blockIdx.x, bh = blk >> 4, seg = blk & 15;
  const int b = bh >> 4, h = bh & 15;
  const float mean = gnp[bh * 2] * (1.f / 131072.f);
  const float var = gnp[bh * 2 + 1] * (1.f / 131072.f) - mean * mean;
  const float rstd = rsqrtf(var + 1e-5f) * 0.2f;  // fold (1-LAMBDA_INIT)
  const int tid = threadIdx.x;
  const int d0 = (tid * 8) & 63;
  const int c = h * 64 + d0;
  fvec4 w0 = *(const fvec4*)(gw + c), w1 = *(const fvec4*)(gw + c + 4);
  fvec4 b0 = *(const fvec4*)(gb + c), b1 = *(const fvec4*)(gb + c + 4);
  float wv[8] = { w0.x, w0.y, w0.z, w0.w, w1.x, w1.y, w1.z, w1.w };
  float bv[8] = { b0.x, b0.y, b0.z, b0.w, b1.x, b1.y, b1.z, b1.w };
  const bf16* xp = Xb + (size_t)bh * 131072;
#pragma unroll
  for (int jj = 0; jj < 4; jj++) {
    const int e = seg * 8192 + (tid + jj * 256) * 8;
    const int srow = e >> 6;
    s16x8 xv = *(const s16x8*)(xp + e);
    bf16 o8[8];
#pragma unroll
    for (int k = 0; k < 8; k++) {
      const float xf = __uint_as_float(((unsigned)(unsigned short)xv[k]) << 16);
      o8[k] = bf16((xf - mean) * rstd * wv[k] + 0.2f * bv[k]);
    }
    *(s16x8*)(Xn + ((size_t)b * NB_S + srow) * 1024 + c) = *(const s16x8*)o8;
  }
}

// ---------------- launch ----------------
extern "C" void kernel_launch(void* const* d_in, const int* in_sizes, int n_in,
                              void* d_out, int out_size, void* d_ws, size_t ws_size,
                              hipStream_t stream) {
  const float* inputs = (const float*)d_in[0];
  const float* amask  = (const float*)d_in[1];
  const int*   tok    = (const int*)d_in[2];
  const float* Wq = (const float*)d_in[3];
  const float* Wk = (const float*)d_in[4];
  const float* Wv = (const float*)d_in[5];
  const float* Wo = (const float*)d_in[6];
  const float* lq1 = (const float*)d_in[7];
  const float* lq2 = (const float*)d_in[8];
  const float* lk1 = (const float*)d_in[9];
  const float* lk2 = (const float*)d_in[10];
  const float* gw = (const float*)d_in[11];
  const float* gb = (const float*)d_in[12];
  float* out = (float*)d_out;
  char* ws = (char*)d_ws;

  bf16* Xbf = (bf16*)(ws + 0);
  bf16* Wqb = (bf16*)(ws + 8388608);       // Wqb||Wkb||Wvb contiguous -> fused QKV
  bf16* Wkb = (bf16*)(ws + 12582912);
  bf16* Wvb = (bf16*)(ws + 16777216);      // dead after QKV gemm
  bf16* Xb  = (bf16*)(ws + 0);             // attn out bf16; aliases Xbf (dead by attn)
  float* comboAlias = (float*)(ws + 16777216);  // aliases Wvb (fallback path)
  bf16* Qb  = (bf16*)(ws + 18874368);
  bf16* Xn  = (bf16*)(ws + 18874368);      // aliases Qb (dead after attn)
  bf16* Kb  = (bf16*)(ws + 35651584);
  bf16* Vtb = (bf16*)(ws + 52428800);
  bf16* Wob = (bf16*)(ws + 60817408);
  float* lam = (float*)(ws + 62914560);
  float* gnp = (float*)(ws + 62914816);    // 128 floats (zeroed in prep)
  float* comboFresh = (float*)(ws + 62915584);  // 256KB fresh space (if ws allows)

  const bool foldCombo = (ws_size >= (size_t)62915584 + 262144);
  float* combo = foldCombo ? comboFresh : comboAlias;

  const float QSCALE = 0.125f * 1.44269504088896340736f;  // 1/sqrt(D) * log2(e)

  prep_kernel<<<foldCombo ? 10497 : 10241, 256, 0, stream>>>(
      inputs, Wq, Wk, Wv, Wo, lq1, lq2, lk1, lk2, tok, amask,
      Xbf, Wqb, Wkb, Wvb, Wob, lam, gnp, combo);

  // fused Q+K+V projection: B = Wqb||Wkb||Wvb (N=5120)
  gemm_bt<0><<<dim3(32, 40), 256, 0, stream>>>(Xbf, Wqb, Qb, Kb, Vtb, nullptr, 1024, QSCALE);

  if (!foldCombo)
    combo_kernel<<<256, 256, 0, stream>>>(tok, amask, combo);

  attn_kernel<<<512, 512, 0, stream>>>(Qb, Kb, Vtb, combo, lam, Xb, gnp);

  gn_apply<<<512, 256, 0, stream>>>(Xb, gnp, gw, gb, Xn);

  gemm_out64<<<dim3(64, 8), 256, 0, stream>>>(Xn, Wob, out);
}